// Round 2
// baseline (17094.069 us; speedup 1.0000x reference)
//
#include <hip/hip_runtime.h>
#include <cstdint>
#include <cstddef>
#include <cfloat>

// Persistent fused Seq2Seq LSTM (B=32,S=T=64,E=256,H=512,V=32000), fp32.
//  - ONE persistent kernel: 256 WGs x 256 thr, ~98KB LDS/WG -> 1 WG/CU by LDS
//    capacity -> all 256 WGs co-resident -> hand-rolled grid barrier is safe
//    (device-scope atomics + fences per G16; no cooperative API needed).
//  - Cell weights LDS-resident for a whole phase (enc staged once, dec staged
//    once). c-state in registers (each (b,j) owned by one thread forever).
//  - Encoder pipelined: phase s runs cell0(s) and cell1(s-1) -> 1 gridsync per
//    phase (both only read h0(s-1)).
//  - Decoder: 3 gridsyncs/step; argmax folded into next-step prologue
//    (every WG redundantly reduces the 256x32 candidate table from LDS->reg).
//  - fc: 250 WGs x 128 rows, reg-prefetch chunked W streaming (8 rows/chunk),
//    padded LDS layout (68-float kq stride -> 8 distinct start banks, 2-way
//    broadcast ds_read_b128 = conflict-free), logits staged in LDS -> aligned
//    float4 stores.

#define NWG   256
#define NTHR  256
#define BSZ   32
#define SLEN  64
#define TLEN  64
#define EDIM  256
#define HDIM  512
#define VOUT  32000
#define FCWGS 250
#define FCR   128
#define FCCH  8
#define NCHK  (FCR / FCCH)
#define HS    68            // 64 + 4 pad (floats)

struct SMem {
    float w0[8 * (8 * (EDIM / 8 + 4) + 8 * HS)];   // 8 rows cell0: 6656 f
    float w1[8 * (8 * (HDIM / 8 + 4) + 8 * HS)];   // 8 rows cell1: 8704 f
    float fcbuf[FCCH * 8 * HS];                    // 4352 f
    float ls[FCR * 33];                            // 4224 f
    float zsh[8 * 32];
    float bsum0[8], bsum1[8];
    float fcb_s[FCR];
    int   ltok[BSZ];
    int   llen[BSZ];
};

// ---------------------------------------------------------- grid barrier ----
__device__ __forceinline__ void gridbar(unsigned* cnt, unsigned* sense, unsigned& epoch)
{
    __syncthreads();
    if (threadIdx.x == 0) {
        epoch++;
        __threadfence();
        unsigned prev = __hip_atomic_fetch_add(cnt, 1u, __ATOMIC_ACQ_REL,
                                               __HIP_MEMORY_SCOPE_AGENT);
        if (prev == NWG - 1) {
            __hip_atomic_store(cnt, 0u, __ATOMIC_RELAXED, __HIP_MEMORY_SCOPE_AGENT);
            __hip_atomic_store(sense, epoch, __ATOMIC_RELEASE, __HIP_MEMORY_SCOPE_AGENT);
        } else {
            while (__hip_atomic_load(sense, __ATOMIC_ACQUIRE,
                                     __HIP_MEMORY_SCOPE_AGENT) != epoch)
                __builtin_amdgcn_s_sleep(1);
        }
        __threadfence();
    }
    __syncthreads();
}

// ------------------------------------------------------- weight staging -----
template<int KIN>
__device__ __forceinline__ void stage_cell_w(float* dst,
        const float* __restrict__ Wih, const float* __restrict__ Whh,
        const float* __restrict__ bih, const float* __restrict__ bhh,
        float* bsum, int j0)
{
    constexpr int XC = KIN / 8, XS = XC + 4, RS = 8 * XS + 8 * HS;
    const int tid = threadIdx.x;
    constexpr int nf4x = KIN / 4;
    for (int tt = tid; tt < 8 * nf4x; tt += NTHR) {
        int r = tt / nf4x, k = (tt % nf4x) * 4;
        int row = (r >> 1) * HDIM + j0 + (r & 1);
        float4 v = *(const float4*)(Wih + (size_t)row * KIN + k);
        *(float4*)(dst + r * RS + (k / XC) * XS + (k % XC)) = v;
    }
    for (int tt = tid; tt < 8 * 128; tt += NTHR) {
        int r = tt >> 7, k = (tt & 127) * 4;
        int row = (r >> 1) * HDIM + j0 + (r & 1);
        float4 v = *(const float4*)(Whh + (size_t)row * HDIM + k);
        *(float4*)(dst + r * RS + 8 * XS + (k >> 6) * HS + (k & 63)) = v;
    }
    if (tid < 8) {
        int row = (tid >> 1) * HDIM + j0 + (tid & 1);
        bsum[tid] = bih[row] + bhh[row];
    }
}

// ------------------------------------------------------------- LSTM cell ----
template<int KIN>
__device__ __forceinline__ void cell_run(const float* w, const float* bsum,
        const float* __restrict__ xrow, const float* __restrict__ hin,
        float* __restrict__ hout, float& creg,
        bool domask, const int* llen, int s, float* zsh, int j0)
{
    constexpr int XC = KIN / 8, XS = XC + 4, RS = 8 * XS + 8 * HS;
    const int tid = threadIdx.x;
    const int wv = tid >> 6, lane = tid & 63, bl = lane >> 3, kq = lane & 7;
    const int b = wv * 8 + bl;

    float4 xr[XC / 4];
#pragma unroll
    for (int i = 0; i < XC / 4; i++)
        xr[i] = *(const float4*)(xrow + kq * XC + i * 4);
    float4 hr[16];
    const float* hp = hin + (size_t)b * HDIM + kq * 64;
#pragma unroll
    for (int i = 0; i < 16; i++) hr[i] = *(const float4*)(hp + i * 4);

    __syncthreads();   // zsh free (previous consumers done)
#pragma unroll
    for (int r = 0; r < 8; r++) {
        float acc = 0.f;
        const float* wx = w + r * RS + kq * XS;
#pragma unroll
        for (int i = 0; i < XC / 4; i++) {
            float4 t4 = *(const float4*)(wx + i * 4);
            acc += t4.x * xr[i].x + t4.y * xr[i].y + t4.z * xr[i].z + t4.w * xr[i].w;
        }
        const float* wh = w + r * RS + 8 * XS + kq * HS;
#pragma unroll
        for (int i = 0; i < 16; i++) {
            float4 t4 = *(const float4*)(wh + i * 4);
            acc += t4.x * hr[i].x + t4.y * hr[i].y + t4.z * hr[i].z + t4.w * hr[i].w;
        }
        acc += __shfl_xor(acc, 1);
        acc += __shfl_xor(acc, 2);
        acc += __shfl_xor(acc, 4);
        if (kq == 0) zsh[r * 32 + b] = acc + bsum[r];
    }
    __syncthreads();
    if (tid < 64) {
        int jl = tid >> 5, bb = tid & 31;
        int j = j0 + jl;
        float zi = zsh[(0 + jl) * 32 + bb], zf = zsh[(2 + jl) * 32 + bb];
        float zg = zsh[(4 + jl) * 32 + bb], zo = zsh[(6 + jl) * 32 + bb];
        float iv = 1.f / (1.f + expf(-zi));
        float fv = 1.f / (1.f + expf(-zf));
        float gv = tanhf(zg);
        float ov = 1.f / (1.f + expf(-zo));
        float c2 = fv * creg + iv * gv;
        float h2 = ov * tanhf(c2);
        size_t off = (size_t)bb * HDIM + j;
        bool m = domask ? (s < llen[bb]) : true;
        float hold = hin[off];
        hout[off] = m ? h2 : hold;
        creg      = m ? c2 : creg;
    }
}

// --------------------------------------------------------------------- fc ---
__device__ __forceinline__ void fc_run(SMem* sm, const float* __restrict__ h,
        const float* __restrict__ fcW, float* __restrict__ out, int t, int g,
        float* __restrict__ cand_val, int* __restrict__ cand_idx)
{
    const int tid = threadIdx.x;
    const int wv = tid >> 6, lane = tid & 63, bl = lane >> 3, kq = lane & 7;
    const int b = wv * 8 + bl;
    const int v0 = g * FCR;

    float4 hr[16];
    const float* hp = h + (size_t)b * HDIM + kq * 64;
#pragma unroll
    for (int i = 0; i < 16; i++) hr[i] = *(const float4*)(hp + i * 4);

    float4 pf[4];
#pragma unroll
    for (int j = 0; j < 4; j++) {
        int tt = tid + j * NTHR;
        int r = tt >> 7, k = (tt & 127) * 4;
        pf[j] = *(const float4*)(fcW + (size_t)(v0 + r) * HDIM + k);
    }

    float mval = -FLT_MAX; int midx = 0x7fffffff;

    for (int c = 0; c < NCHK; c++) {
        __syncthreads();     // previous chunk's compute done
#pragma unroll
        for (int j = 0; j < 4; j++) {
            int tt = tid + j * NTHR;
            int r = tt >> 7, k = (tt & 127) * 4;
            *(float4*)(sm->fcbuf + r * (8 * HS) + (k >> 6) * HS + (k & 63)) = pf[j];
        }
        if (c + 1 < NCHK) {
#pragma unroll
            for (int j = 0; j < 4; j++) {
                int tt = tid + j * NTHR;
                int r = tt >> 7, k = (tt & 127) * 4;
                pf[j] = *(const float4*)(fcW + (size_t)(v0 + (c + 1) * FCCH + r) * HDIM + k);
            }
        }
        __syncthreads();
#pragma unroll
        for (int r = 0; r < FCCH; r++) {
            float acc = 0.f;
            const float* wp = sm->fcbuf + r * (8 * HS) + kq * HS;
#pragma unroll
            for (int i = 0; i < 16; i++) {
                float4 w4 = *(const float4*)(wp + i * 4);
                acc += w4.x * hr[i].x + w4.y * hr[i].y + w4.z * hr[i].z + w4.w * hr[i].w;
            }
            acc += __shfl_xor(acc, 1);
            acc += __shfl_xor(acc, 2);
            acc += __shfl_xor(acc, 4);
            if (kq == 0) {
                int gr = c * FCCH + r;
                float z = acc + sm->fcb_s[gr];
                sm->ls[gr * 33 + b] = z;
                if (z > mval) { mval = z; midx = v0 + gr; }  // ascending gr: '>' keeps first
            }
        }
    }
    if (kq == 0) {
        cand_val[b * NWG + g] = mval;
        cand_idx[b * NWG + g] = midx;
    }
    __syncthreads();
    // logits: 4 iters of (8 b x 32 q), aligned float4 (v0 = g*128)
#pragma unroll
    for (int bo = 0; bo < 4; bo++) {
        int b_l = tid >> 5, q = tid & 31;
        int bb = bo * 8 + b_l;
        float4 v;
        v.x = sm->ls[(q * 4 + 0) * 33 + bb];
        v.y = sm->ls[(q * 4 + 1) * 33 + bb];
        v.z = sm->ls[(q * 4 + 2) * 33 + bb];
        v.w = sm->ls[(q * 4 + 3) * 33 + bb];
        *(float4*)(out + ((size_t)bb * TLEN + t) * VOUT + v0 + q * 4) = v;
    }
}

// --------------------------------------------------------- main persistent --
__global__ __launch_bounds__(256, 1)
void seq2seq_persist(
    const int* __restrict__ inputs, const int* __restrict__ lens,
    const float* __restrict__ enc_emb, const float* __restrict__ dec_emb,
    const float* __restrict__ eW0ih, const float* __restrict__ eW0hh,
    const float* __restrict__ eB0ih, const float* __restrict__ eB0hh,
    const float* __restrict__ eW1ih, const float* __restrict__ eW1hh,
    const float* __restrict__ eB1ih, const float* __restrict__ eB1hh,
    const float* __restrict__ dW0ih, const float* __restrict__ dW0hh,
    const float* __restrict__ dB0ih, const float* __restrict__ dB0hh,
    const float* __restrict__ dW1ih, const float* __restrict__ dW1hh,
    const float* __restrict__ dB1ih, const float* __restrict__ dB1hh,
    const float* __restrict__ fcW, const float* __restrict__ fcb,
    float* __restrict__ out,
    float* h0a, float* h0b, float* h1a, float* h1b,
    float* cand_val, int* cand_idx, unsigned* bar)
{
    __shared__ SMem sm;
    const int g = blockIdx.x;
    const int tid = threadIdx.x;
    const int j0 = g * 2;
    unsigned epoch = 0;

    const int wv = tid >> 6, lane = tid & 63, bl = lane >> 3;
    const int b = wv * 8 + bl;

    float* h0[2] = { h0a, h0b };
    float* h1[2] = { h1a, h1b };

    // ---- encoder phase ----
    stage_cell_w<EDIM>(sm.w0, eW0ih, eW0hh, eB0ih, eB0hh, sm.bsum0, j0);
    stage_cell_w<HDIM>(sm.w1, eW1ih, eW1hh, eB1ih, eB1hh, sm.bsum1, j0);
    if (tid < BSZ) sm.llen[tid] = lens[tid];
    float c0r = 0.f, c1r = 0.f;
    __syncthreads();

    for (int s = 0; s <= SLEN; ++s) {
        int pp = s & 1;
        if (s < SLEN) {
            int tokv = inputs[b * SLEN + s];
            const float* xrow = enc_emb + (size_t)tokv * EDIM;
            cell_run<EDIM>(sm.w0, sm.bsum0, xrow, h0[pp], h0[pp ^ 1], c0r,
                           true, sm.llen, s, sm.zsh, j0);
        }
        if (s >= 1) {
            int q = (s - 1) & 1;
            cell_run<HDIM>(sm.w1, sm.bsum1, h0[pp] + (size_t)b * HDIM,
                           h1[q], h1[q ^ 1], c1r, true, sm.llen, s - 1, sm.zsh, j0);
        }
        gridbar(bar, bar + 1, epoch);
    }

    // ---- decoder setup ----
    stage_cell_w<EDIM>(sm.w0, dW0ih, dW0hh, dB0ih, dB0hh, sm.bsum0, j0);
    stage_cell_w<HDIM>(sm.w1, dW1ih, dW1hh, dB1ih, dB1hh, sm.bsum1, j0);
    if (g < FCWGS) {
        for (int i = tid; i < FCR; i += NTHR) sm.fcb_s[i] = fcb[g * FCR + i];
    } else if (tid < BSZ) {
        cand_val[tid * NWG + g] = -FLT_MAX;
        cand_idx[tid * NWG + g] = 0x7fffffff;
    }
    c0r = 0.f; c1r = 0.f;
    __syncthreads();

    // ---- decoder loop ----
    for (int t = 0; t < TLEN; ++t) {
        int pp = t & 1;
        if (t == 0) {
            if (tid < BSZ) sm.ltok[tid] = 1;
        } else {
            int bb = tid >> 3, q = tid & 7;
            float bv = -FLT_MAX; int bi = 0x7fffffff;
            for (int i = 0; i < 32; i++) {
                int gg = q * 32 + i;
                float v = cand_val[bb * NWG + gg];
                int  ix = cand_idx[bb * NWG + gg];
                if (v > bv || (v == bv && ix < bi)) { bv = v; bi = ix; }
            }
#pragma unroll
            for (int m = 1; m < 8; m <<= 1) {
                float ov = __shfl_xor(bv, m); int oi = __shfl_xor(bi, m);
                if (ov > bv || (ov == bv && oi < bi)) { bv = ov; bi = oi; }
            }
            if (q == 0) sm.ltok[bb] = bi;
        }
        __syncthreads();
        const float* xrow = dec_emb + (size_t)sm.ltok[b] * EDIM;
        cell_run<EDIM>(sm.w0, sm.bsum0, xrow, h0[pp], h0[pp ^ 1], c0r,
                       false, nullptr, 0, sm.zsh, j0);
        gridbar(bar, bar + 1, epoch);
        cell_run<HDIM>(sm.w1, sm.bsum1, h0[pp ^ 1] + (size_t)b * HDIM,
                       h1[pp], h1[pp ^ 1], c1r, false, nullptr, 0, sm.zsh, j0);
        gridbar(bar, bar + 1, epoch);
        if (g < FCWGS)
            fc_run(&sm, h1[pp ^ 1], fcW, out, t, g, cand_val, cand_idx);
        gridbar(bar, bar + 1, epoch);
    }
}

// ------------------------------------------------------------------- init ---
__global__ void initk(float* hbufs, unsigned* bar)
{
    int i = blockIdx.x * 256 + threadIdx.x;
    if (i < 4 * BSZ * HDIM) hbufs[i] = 0.f;
    if (i < 2) bar[i] = 0u;
}

// ----------------------------------------------------------------- driver ---
extern "C" void kernel_launch(void* const* d_in, const int* in_sizes, int n_in,
                              void* d_out, int out_size, void* d_ws, size_t ws_size,
                              hipStream_t stream)
{
    const int*   inputs  = (const int*)d_in[0];
    const int*   lens    = (const int*)d_in[3];
    const float* enc_emb = (const float*)d_in[4];
    const float* dec_emb = (const float*)d_in[5];
    const float* W[16];
    for (int i = 0; i < 16; i++) W[i] = (const float*)d_in[6 + i];
    const float* fcW = (const float*)d_in[22];
    const float* fcb = (const float*)d_in[23];
    float* out = (float*)d_out;

    float* ws = (float*)d_ws;
    float* h0a = ws;
    float* h0b = ws + 16384;
    float* h1a = ws + 32768;
    float* h1b = ws + 49152;
    float* cand_val = ws + 65536;                 // 32*256
    int*   cand_idx = (int*)(ws + 73728);         // 32*256
    unsigned* bar   = (unsigned*)(ws + 81920);    // 2

    initk<<<256, 256, 0, stream>>>(ws, bar);
    seq2seq_persist<<<NWG, NTHR, 0, stream>>>(
        inputs, lens, enc_emb, dec_emb,
        W[0], W[1], W[2], W[3], W[4], W[5], W[6], W[7],
        W[8], W[9], W[10], W[11], W[12], W[13], W[14], W[15],
        fcW, fcb, out,
        h0a, h0b, h1a, h1b, cand_val, cand_idx, bar);
}

// Round 3
// 7372.672 us; speedup vs baseline: 2.3186x; 2.3186x over previous
//
#include <hip/hip_runtime.h>
#include <cstdint>
#include <cstddef>
#include <cfloat>

// Seq2Seq LSTM (B=32,S=T=64,E=256,H=512,V=32000), fp32, multi-dispatch.
// R3: reverted persistent design (grid-barrier cost ~55us/sync, LDS broadcast
// amplification). Changes vs R1:
//  - fc: 4-way register reuse of W (lane = 16kq x 4bg, 4 b's per lane,
//    h in 128 VGPRs) -> LDS W traffic /4; 1600 WGs x 20 rows, ~50KB LDS,
//    3 WGs/CU; single-shot staging; padded stride 36 (2-way max = free).
//  - encoder pipelined: one dispatch per step runs cell0(s) || cell1(s-1).

#define BSZ  32
#define SLEN 64
#define TLEN 64
#define EDIM 256
#define HDIM 512
#define VOUT 32000
#define FCRW 20
#define FCWG (VOUT / FCRW)   // 1600

// ------------------------------------------------------------- LSTM cell ----
// Each WG owns 2 j-columns x 4 gates (8 z-rows) for all 32 batch rows.
// sm layout: [8*RS weights][8*32 zsh]
template<int KIN>
__device__ __forceinline__ void cell_body(float* sm, int j0,
        const float* __restrict__ xbase, const int* __restrict__ xidx,
        int xstride, int xoff,
        const float* __restrict__ Wih, const float* __restrict__ Whh,
        const float* __restrict__ bih, const float* __restrict__ bhh,
        const float* __restrict__ hin, float* __restrict__ hout,
        float* __restrict__ cbuf, const int* __restrict__ lens, int s)
{
    constexpr int XC = KIN / 8;       // per-lane x floats
    constexpr int XS = XC + 4;        // padded chunk stride
    constexpr int HS = 64 + 4;
    constexpr int RS = 8 * XS + 8 * HS;
    float* wsm = sm;
    float* zsh = sm + 8 * RS;

    const int tid = threadIdx.x;

    // stage 8 weight rows [Wih | Whh]
    {
        constexpr int nf4x = KIN / 4;
        for (int tt = tid; tt < 8 * nf4x; tt += 256) {
            int r = tt / nf4x, k = (tt % nf4x) * 4;
            int row = (r >> 1) * HDIM + j0 + (r & 1);
            float4 v = *(const float4*)(Wih + (size_t)row * KIN + k);
            *(float4*)(wsm + r * RS + (k / XC) * XS + (k % XC)) = v;
        }
        for (int tt = tid; tt < 8 * 128; tt += 256) {
            int r = tt >> 7, k = (tt & 127) * 4;
            int row = (r >> 1) * HDIM + j0 + (r & 1);
            float4 v = *(const float4*)(Whh + (size_t)row * HDIM + k);
            *(float4*)(wsm + r * RS + 8 * XS + (k >> 6) * HS + (k & 63)) = v;
        }
    }

    const int wv = tid >> 6, lane = tid & 63, bl = lane >> 3, kq = lane & 7;
    const int b = wv * 8 + bl;

    const float* xrow = xidx ? xbase + (size_t)xidx[b * xstride + xoff] * KIN
                             : xbase + (size_t)b * KIN;
    float4 xr[XC / 4];
#pragma unroll
    for (int i = 0; i < XC / 4; i++)
        xr[i] = *(const float4*)(xrow + kq * XC + i * 4);
    float4 hr[16];
    const float* hp = hin + (size_t)b * HDIM + kq * 64;
#pragma unroll
    for (int i = 0; i < 16; i++) hr[i] = *(const float4*)(hp + i * 4);

    __syncthreads();

#pragma unroll
    for (int r = 0; r < 8; r++) {
        float acc = 0.f;
        const float* wx = wsm + r * RS + kq * XS;
#pragma unroll
        for (int i = 0; i < XC / 4; i++) {
            float4 t4 = *(const float4*)(wx + i * 4);
            acc += t4.x * xr[i].x + t4.y * xr[i].y + t4.z * xr[i].z + t4.w * xr[i].w;
        }
        const float* wh = wsm + r * RS + 8 * XS + kq * HS;
#pragma unroll
        for (int i = 0; i < 16; i++) {
            float4 t4 = *(const float4*)(wh + i * 4);
            acc += t4.x * hr[i].x + t4.y * hr[i].y + t4.z * hr[i].z + t4.w * hr[i].w;
        }
        acc += __shfl_xor(acc, 1);
        acc += __shfl_xor(acc, 2);
        acc += __shfl_xor(acc, 4);
        if (kq == 0) zsh[r * 32 + b] = acc;
    }
    __syncthreads();

    if (tid < 64) {
        int jl = tid >> 5, bb = tid & 31;
        int j = j0 + jl;
        float zi = zsh[(0 + jl) * 32 + bb] + bih[0 * HDIM + j] + bhh[0 * HDIM + j];
        float zf = zsh[(2 + jl) * 32 + bb] + bih[1 * HDIM + j] + bhh[1 * HDIM + j];
        float zg = zsh[(4 + jl) * 32 + bb] + bih[2 * HDIM + j] + bhh[2 * HDIM + j];
        float zo = zsh[(6 + jl) * 32 + bb] + bih[3 * HDIM + j] + bhh[3 * HDIM + j];
        float iv = 1.f / (1.f + expf(-zi));
        float fv = 1.f / (1.f + expf(-zf));
        float gv = tanhf(zg);
        float ov = 1.f / (1.f + expf(-zo));
        size_t off = (size_t)bb * HDIM + j;
        float cold = cbuf[off];
        float c2 = fv * cold + iv * gv;
        float h2 = ov * tanhf(c2);
        bool m = lens ? (s < lens[bb]) : true;
        hout[off] = m ? h2 : hin[off];
        cbuf[off] = m ? c2 : cold;
    }
}

// standalone cell (decoder)
template<int KIN>
__global__ __launch_bounds__(256)
void cell_k(const float* __restrict__ xbase, const int* __restrict__ xidx,
            int xstride, int xoff,
            const float* __restrict__ Wih, const float* __restrict__ Whh,
            const float* __restrict__ bih, const float* __restrict__ bhh,
            const float* __restrict__ hin, float* __restrict__ hout,
            float* __restrict__ cbuf, const int* __restrict__ lens, int s)
{
    constexpr int RS = 8 * (KIN / 8 + 4) + 8 * 68;
    __shared__ __align__(16) float sm[8 * RS + 8 * 32];
    cell_body<KIN>(sm, blockIdx.x * 2, xbase, xidx, xstride, xoff,
                   Wih, Whh, bih, bhh, hin, hout, cbuf, lens, s);
}

// fused encoder step: WGs 0..255 -> cell0(s), 256..511 -> cell1(s-1)
__global__ __launch_bounds__(256)
void enc_step_k(const int* __restrict__ inputs, const int* __restrict__ lens,
                const float* __restrict__ enc_emb,
                const float* __restrict__ W0ih, const float* __restrict__ W0hh,
                const float* __restrict__ B0ih, const float* __restrict__ B0hh,
                const float* __restrict__ W1ih, const float* __restrict__ W1hh,
                const float* __restrict__ B1ih, const float* __restrict__ B1hh,
                float* h0a, float* h0b, float* h1a, float* h1b,
                float* c0, float* c1, int s)
{
    extern __shared__ float sm[];
    float* h0[2] = { h0a, h0b };
    float* h1[2] = { h1a, h1b };
    int p = s & 1;
    if (blockIdx.x < 256) {
        if (s < SLEN)
            cell_body<EDIM>(sm, blockIdx.x * 2, enc_emb, inputs, SLEN, s,
                            W0ih, W0hh, B0ih, B0hh, h0[p], h0[p ^ 1], c0, lens, s);
    } else {
        if (s >= 1) {
            int q = (s - 1) & 1;
            cell_body<HDIM>(sm, (blockIdx.x - 256) * 2, h0[p], nullptr, 0, 0,
                            W1ih, W1hh, B1ih, B1hh, h1[q], h1[q ^ 1], c1, lens, s - 1);
        }
    }
}

// --------------------------------------------------------------------- fc ---
// lane = (kq:0..15, bg:0..3); wave covers 16 b (4 per lane) for 10 rows.
// waves 0,1: rows 0..9 (b 0-15 / 16-31); waves 2,3: rows 10..19.
__global__ __launch_bounds__(256)
void fc_k(const float* __restrict__ h, const float* __restrict__ fcW,
          const float* __restrict__ fcb, float* __restrict__ out, int t,
          float* __restrict__ cand_val, int* __restrict__ cand_idx)
{
    __shared__ __align__(16) float wsm[FCRW * 576];   // 46KB, slice stride 36
    __shared__ float ls[FCRW * 33];
    __shared__ float cmx[BSZ];
    __shared__ int   cmi[BSZ];
    const int tid = threadIdx.x, g = blockIdx.x;
    const int v0 = g * FCRW;

    // stage 20 rows (coalesced float4; 16B-aligned LDS: slice stride 36f=144B)
    for (int i = tid; i < FCRW * 128; i += 256) {
        int r = i >> 7, k = (i & 127) * 4;
        float4 w = *(const float4*)(fcW + (size_t)(v0 + r) * HDIM + k);
        *(float4*)(wsm + r * 576 + (k >> 5) * 36 + (k & 31)) = w;
    }

    const int wv = tid >> 6, lane = tid & 63;
    const int kq = lane & 15, bg = lane >> 4;
    const int bb = (wv & 1) * 16 + bg * 4;    // this lane's 4 b's: bb..bb+3
    const int r0 = (wv >> 1) * 10;

    float4 hreg[4][8];
#pragma unroll
    for (int j = 0; j < 4; j++)
#pragma unroll
        for (int i = 0; i < 8; i++)
            hreg[j][i] = *(const float4*)(h + (size_t)(bb + j) * HDIM + kq * 32 + i * 4);

    __syncthreads();

    float vmax[4]; int vidx[4];
#pragma unroll
    for (int j = 0; j < 4; j++) { vmax[j] = -FLT_MAX; vidx[j] = 0; }

    for (int r = 0; r < 10; r++) {
        const float* wp = wsm + (r0 + r) * 576 + kq * 36;
        float a0 = 0.f, a1 = 0.f, a2 = 0.f, a3 = 0.f;
#pragma unroll
        for (int i = 0; i < 8; i++) {
            float4 w = *(const float4*)(wp + i * 4);
            a0 += w.x * hreg[0][i].x + w.y * hreg[0][i].y + w.z * hreg[0][i].z + w.w * hreg[0][i].w;
            a1 += w.x * hreg[1][i].x + w.y * hreg[1][i].y + w.z * hreg[1][i].z + w.w * hreg[1][i].w;
            a2 += w.x * hreg[2][i].x + w.y * hreg[2][i].y + w.z * hreg[2][i].z + w.w * hreg[2][i].w;
            a3 += w.x * hreg[3][i].x + w.y * hreg[3][i].y + w.z * hreg[3][i].z + w.w * hreg[3][i].w;
        }
#pragma unroll
        for (int m = 1; m < 16; m <<= 1) {
            a0 += __shfl_xor(a0, m);
            a1 += __shfl_xor(a1, m);
            a2 += __shfl_xor(a2, m);
            a3 += __shfl_xor(a3, m);
        }
        if (kq == 0) {
            int vrow = v0 + r0 + r;
            float bias = fcb[vrow];
            float z[4] = { a0 + bias, a1 + bias, a2 + bias, a3 + bias };
#pragma unroll
            for (int j = 0; j < 4; j++) {
                ls[(r0 + r) * 33 + bb + j] = z[j];
                if (z[j] > vmax[j]) { vmax[j] = z[j]; vidx[j] = vrow; } // first-max
            }
        }
    }

    // merge candidates across the two row-halves
    if ((wv >> 1) == 1 && kq == 0) {
#pragma unroll
        for (int j = 0; j < 4; j++) { cmx[bb + j] = vmax[j]; cmi[bb + j] = vidx[j]; }
    }
    __syncthreads();
    if ((wv >> 1) == 0 && kq == 0) {
#pragma unroll
        for (int j = 0; j < 4; j++) {
            float v2 = cmx[bb + j]; int i2 = cmi[bb + j];
            // rows of half A (r0=0) are lower indices; '>' keeps A on tie
            if (v2 > vmax[j] || (v2 == vmax[j] && i2 < vidx[j])) { vmax[j] = v2; vidx[j] = i2; }
            cand_val[(size_t)(bb + j) * FCWG + g] = vmax[j];
            cand_idx[(size_t)(bb + j) * FCWG + g] = vidx[j];
        }
    }

    // logits out: 32 b x 5 float4 (20 rows); v0 multiple of 4 -> aligned
    {
        int b2 = tid >> 3, c8 = tid & 7;
        if (c8 < 5) {
            float4 vv;
            vv.x = ls[(c8 * 4 + 0) * 33 + b2];
            vv.y = ls[(c8 * 4 + 1) * 33 + b2];
            vv.z = ls[(c8 * 4 + 2) * 33 + b2];
            vv.w = ls[(c8 * 4 + 3) * 33 + b2];
            *(float4*)(out + ((size_t)b2 * TLEN + t) * VOUT + v0 + c8 * 4) = vv;
        }
    }
}

// ----------------------------------------------------------------- argmax ---
__global__ __launch_bounds__(256)
void argmax_k(const float* __restrict__ cand_val, const int* __restrict__ cand_idx,
              int* __restrict__ tok)
{
    __shared__ float sv[256];
    __shared__ int   si[256];
    int b = blockIdx.x, tid = threadIdx.x;
    float bv = -FLT_MAX; int bi = 0x7fffffff;
    for (int gg = tid; gg < FCWG; gg += 256) {
        float v = cand_val[(size_t)b * FCWG + gg];
        int  ix = cand_idx[(size_t)b * FCWG + gg];
        if (v > bv || (v == bv && ix < bi)) { bv = v; bi = ix; }
    }
    sv[tid] = bv; si[tid] = bi;
    __syncthreads();
    for (int stp = 128; stp > 0; stp >>= 1) {
        if (tid < stp) {
            float v = sv[tid + stp]; int ix = si[tid + stp];
            if (v > sv[tid] || (v == sv[tid] && ix < si[tid])) { sv[tid] = v; si[tid] = ix; }
        }
        __syncthreads();
    }
    if (tid == 0) tok[b] = si[0];
}

// ------------------------------------------------------------------- init ---
__global__ void init_enc(float* h0a, float* h1a, float* c0, float* c1)
{
    int i = blockIdx.x * 256 + threadIdx.x;
    if (i < BSZ * HDIM) { h0a[i] = 0.f; h1a[i] = 0.f; c0[i] = 0.f; c1[i] = 0.f; }
}
__global__ void init_dec(float* c0, float* c1, int* tok)
{
    int i = blockIdx.x * 256 + threadIdx.x;
    if (i < BSZ * HDIM) { c0[i] = 0.f; c1[i] = 0.f; }
    if (i < BSZ) tok[i] = 1;
}

// ----------------------------------------------------------------- driver ---
extern "C" void kernel_launch(void* const* d_in, const int* in_sizes, int n_in,
                              void* d_out, int out_size, void* d_ws, size_t ws_size,
                              hipStream_t stream)
{
    const int*   inputs  = (const int*)d_in[0];
    const int*   lens    = (const int*)d_in[3];
    const float* enc_emb = (const float*)d_in[4];
    const float* dec_emb = (const float*)d_in[5];
    const float* W[16];
    for (int i = 0; i < 16; i++) W[i] = (const float*)d_in[6 + i];
    // W[0..7] enc: Wih0,Whh0,bih0,bhh0,Wih1,Whh1,bih1,bhh1 ; W[8..15] dec same
    const float* fcW = (const float*)d_in[22];
    const float* fcb = (const float*)d_in[23];
    float* out = (float*)d_out;

    float* ws = (float*)d_ws;
    float* h0a = ws;
    float* h0b = ws + 16384;
    float* h1a = ws + 32768;
    float* h1b = ws + 49152;
    float* c0  = ws + 65536;
    float* c1  = ws + 81920;
    float* cand_val = ws + 98304;                    // 32*1600
    int*   cand_idx = (int*)(ws + 98304 + 51200);    // 32*1600
    int*   tok      = (int*)(ws + 98304 + 102400);   // 32

    float* h0[2] = { h0a, h0b };
    float* h1[2] = { h1a, h1b };

    init_enc<<<64, 256, 0, stream>>>(h0a, h1a, c0, c1);

    // encoder: pipelined, 65 dispatches; dyn-LDS = cell1 footprint (35840B)
    for (int s = 0; s <= SLEN; s++) {
        enc_step_k<<<512, 256, 36864, stream>>>(
            inputs, lens, enc_emb,
            W[0], W[1], W[2], W[3], W[4], W[5], W[6], W[7],
            h0a, h0b, h1a, h1b, c0, c1, s);
    }
    // encoder finals land in h0[0], h1[0]

    init_dec<<<64, 256, 0, stream>>>(c0, c1, tok);
    for (int t = 0; t < TLEN; t++) {
        int p = t & 1;
        cell_k<EDIM><<<256, 256, 0, stream>>>(dec_emb, tok, 1, 0,
            W[8], W[9], W[10], W[11], h0[p], h0[p ^ 1], c0, nullptr, 0);
        cell_k<HDIM><<<256, 256, 0, stream>>>(h0[p ^ 1], nullptr, 0, 0,
            W[12], W[13], W[14], W[15], h1[p], h1[p ^ 1], c1, nullptr, 0);
        fc_k<<<FCWG, 256, 0, stream>>>(h1[p ^ 1], fcW, fcb, out, t, cand_val, cand_idx);
        argmax_k<<<BSZ, 256, 0, stream>>>(cand_val, cand_idx, tok);
    }
}